// Round 7
// baseline (2217.310 us; speedup 1.0000x reference)
//
#include <hip/hip_runtime.h>

#define NEGV -10000.0f

__device__ __forceinline__ float bf2f(unsigned short u){
  union{unsigned int i; float f;} x; x.i = ((unsigned int)u)<<16; return x.f;
}
__device__ __forceinline__ unsigned short f2bf(float f){
  union{float f; unsigned int i;} x; x.f=f;
  unsigned int i = x.i;
  return (unsigned short)((i + 0x7FFFu + ((i>>16)&1u)) >> 16);
}

// ---------------- K/V projection, scalar fp32 MACs ----------------
// grid (34, 6): mt<17 -> K over concat rows, else V. block 256.
// out[m][n] = sum_k A[m][k] * W[k][n] + b[n], stored bf16 (internal ws).
__global__ __launch_bounds__(256) void kv_proj(
    const float* __restrict__ word, const float* __restrict__ ent,
    const float* __restrict__ k_w, const float* __restrict__ k_b,
    const float* __restrict__ v_w, const float* __restrict__ v_b,
    unsigned short* __restrict__ Kb, unsigned short* __restrict__ Vb)
{
  int mt = blockIdx.x, nt = blockIdx.y;
  int g  = (mt < 17) ? 0 : 1;
  int mg = g ? (mt - 17) : mt;
  const float* Wm = g ? v_w : k_w;
  const float* Bv = g ? v_b : k_b;
  unsigned short* out = (g ? Vb : Kb) + (size_t)mg*128*768;
  const float* A = (mg < 16) ? (word + (size_t)mg*128*768) : ent;
  int n0 = nt*128;

  __shared__ float a_s[128][33];
  __shared__ float b_s[128][33];

  int tid = threadIdx.x;
  float acc[8][8];
  #pragma unroll
  for (int i=0;i<8;i++)
    #pragma unroll
    for (int j=0;j<8;j++) acc[i][j]=0.f;

  int arow = tid>>1, acol0 = (tid&1)*16;
  int bn   = tid & 127;       // n index within tile
  int bg   = tid >> 7;        // 0/1 -> kk half

  for (int k0=0; k0<768; k0+=32){
    float av[16], bv[16];
    #pragma unroll
    for (int t=0;t<16;t++) av[t] = A[(size_t)arow*768 + k0 + acol0 + t];
    #pragma unroll
    for (int t=0;t<16;t++) bv[t] = Wm[(size_t)(k0 + bg*16 + t)*768 + n0 + bn];
    __syncthreads();
    #pragma unroll
    for (int t=0;t<16;t++) a_s[arow][acol0+t] = av[t];
    #pragma unroll
    for (int t=0;t<16;t++) b_s[bn][bg*16+t]   = bv[t];
    __syncthreads();
    int m8 = (tid>>4)*8, n8 = (tid&15)*8;
    #pragma unroll
    for (int kk=0; kk<32; kk++){
      float a8[8], b8[8];
      #pragma unroll
      for (int i=0;i<8;i++) a8[i] = a_s[m8+i][kk];
      #pragma unroll
      for (int j=0;j<8;j++) b8[j] = b_s[n8+j][kk];
      #pragma unroll
      for (int i=0;i<8;i++)
        #pragma unroll
        for (int j=0;j<8;j++) acc[i][j] += a8[i]*b8[j];
    }
  }
  int m8 = (tid>>4)*8, n8 = (tid&15)*8;
  #pragma unroll
  for (int j=0;j<8;j++){
    float bb = Bv[n0+n8+j];
    #pragma unroll
    for (int i=0;i<8;i++)
      out[(size_t)(m8+i)*768 + n0+n8+j] = f2bf(acc[i][j] + bb);
  }
}

// ---------------- in-kernel Q projection: q[d] = X[i,:] @ W[:, h*64+d] + B[h*64+d] ----
__device__ __forceinline__ void project64(
    const float* __restrict__ X, int i, const float* __restrict__ W,
    const float* __restrict__ Bz, int h, int tid, float (*w_s)[65], float* q)
{
  #pragma unroll
  for (int d=0; d<64; d++) q[d] = Bz[h*64+d];
  for (int k0=0; k0<768; k0+=64){
    __syncthreads();
    #pragma unroll
    for (int ii=0; ii<16; ii++){
      int kk = (tid>>6)*16 + ii;
      w_s[kk][tid&63] = W[(size_t)(k0+kk)*768 + h*64 + (tid&63)];
    }
    __syncthreads();
    for (int kk=0; kk<64; kk++){
      float xv = X[(size_t)i*768 + k0 + kk];
      #pragma unroll
      for (int d=0; d<64; d++) q[d] += xv * w_s[kk][d];
    }
  }
}

// ---------------- fused Q-projection + scalar flash attention (fp32 output) -------
// blocks 0..7: word queries (256 each); block 8: entity queries (128). grid.y = head.
__global__ __launch_bounds__(256) void attn_fq(
  const unsigned short* __restrict__ Kb, const unsigned short* __restrict__ Vb,
  const float* __restrict__ word, const float* __restrict__ ent,
  const float* __restrict__ q_w,   const float* __restrict__ q_b,
  const float* __restrict__ w2e_w, const float* __restrict__ w2e_b,
  const float* __restrict__ e2w_w, const float* __restrict__ e2w_b,
  const float* __restrict__ e2e_w, const float* __restrict__ e2e_b,
  const float* __restrict__ am,
  float* __restrict__ outw, float* __restrict__ oute)
{
  int bx = blockIdx.x, h = blockIdx.y;
  bool isword = bx < 8;
  int tid = threadIdx.x;
  int q0 = isword ? bx*256 : 0;
  bool active = isword || (tid < 128);
  int i = q0 + (active ? tid : 0);          // clamped for inactive lanes

  const float* X  = isword ? word  : ent;
  const float* W1 = isword ? q_w   : e2w_w;  const float* B1 = isword ? q_b   : e2w_b;
  const float* W2 = isword ? w2e_w : e2e_w;  const float* B2 = isword ? w2e_b : e2e_b;

  __shared__ float w_s[64][65];
  __shared__ float ks[16][64];
  __shared__ float vs[16][64];

  float q[64], o[64];
  float m = -1e30f, l = 0.f;
  #pragma unroll
  for (int d=0; d<64; d++) o[d] = 0.f;

  project64(X, i, W1, B1, h, tid, w_s, q);   // phase-1 Q (vs word keys)

  int wlo = isword ? ((q0-256 < 0) ? 0 : q0-256) : 0;
  int whi = isword ? ((q0+511 > 2047) ? 2047 : q0+511) : 2047;
  int nw  = (whi + 1 - wlo) >> 4;            // 16-key tiles (spans divisible by 16)
  int nc  = nw + 8;                          // + 128 entity keys

  int skey = tid>>4, sd4 = (tid&15)*4;

  for (int c=0; c<nc; c++){
    if (c == nw) project64(X, i, W2, B2, h, tid, w_s, q);   // switch to phase-2 Q
    bool entp = c >= nw;
    int j0 = entp ? (2048 + (c-nw)*16) : (wlo + c*16);
    __syncthreads();
    {
      const unsigned short* kp = Kb + (size_t)(j0+skey)*768 + h*64 + sd4;
      const unsigned short* vp = Vb + (size_t)(j0+skey)*768 + h*64 + sd4;
      #pragma unroll
      for (int d=0; d<4; d++){ ks[skey][sd4+d] = bf2f(kp[d]); vs[skey][sd4+d] = bf2f(vp[d]); }
    }
    __syncthreads();
    if (active){
      float s16[16];
      float cmax = -1e30f;
      bool wband = isword && !entp;
      #pragma unroll
      for (int jj=0; jj<16; jj++){
        int j = j0 + jj;
        float dot = 0.f;
        #pragma unroll
        for (int d=0; d<64; d++) dot += q[d]*ks[jj][d];
        float amj = am[j];
        if (wband){
          dot += (amj != 0.f) ? NEGV : 0.f;                           // float_mask pre-add
          bool ok = ((unsigned)(i - j + 256) <= 512u) && (dot != 0.f); // band & !=0 quirk
          dot = ok ? dot : NEGV;
        }
        float lg = dot*0.125f + amj;
        s16[jj] = lg;
        cmax = fmaxf(cmax, lg);
      }
      float mn = fmaxf(m, cmax);
      float alpha = expf(m - mn);
      m = mn;
      l *= alpha;
      #pragma unroll
      for (int d=0; d<64; d++) o[d] *= alpha;
      #pragma unroll
      for (int jj=0; jj<16; jj++){
        float p = expf(s16[jj] - m);
        l += p;
        #pragma unroll
        for (int d=0; d<64; d++) o[d] += p*vs[jj][d];
      }
    }
  }

  if (active){
    float* outp = isword ? (outw + (size_t)i*768) : (oute + (size_t)i*768);
    float inv = 1.f / l;
    #pragma unroll
    for (int d=0; d<64; d++) outp[h*64 + d] = o[d]*inv;
  }
}

extern "C" void kernel_launch(void* const* d_in, const int* in_sizes, int n_in,
                              void* d_out, int out_size, void* d_ws, size_t ws_size,
                              hipStream_t stream) {
  // Input order: setup_inputs() dict order (confirmed by R6 experiment).
  const float* word  = (const float*)d_in[0];
  const float* ent   = (const float*)d_in[1];
  const float* am    = (const float*)d_in[2];
  const float* q_w   = (const float*)d_in[3];
  const float* q_b   = (const float*)d_in[4];
  const float* k_w   = (const float*)d_in[5];
  const float* k_b   = (const float*)d_in[6];
  const float* v_w   = (const float*)d_in[7];
  const float* v_b   = (const float*)d_in[8];
  const float* w2e_w = (const float*)d_in[9];
  const float* w2e_b = (const float*)d_in[10];
  const float* e2w_w = (const float*)d_in[11];
  const float* e2w_b = (const float*)d_in[12];
  const float* e2e_w = (const float*)d_in[13];
  const float* e2e_b = (const float*)d_in[14];

  // ws: only K,V (bf16) -> 2 * 2176*768*2 B = 6.7 MB
  unsigned short* Kb = (unsigned short*)d_ws;
  unsigned short* Vb = Kb + (size_t)2176*768;

  // OUTPUT IS FP32 (reference output dtype) — this was the bug in R3-R6.
  float* outw = (float*)d_out;
  float* oute = outw + (size_t)2048*768;

  hipLaunchKernelGGL(kv_proj, dim3(34,6), dim3(256), 0, stream,
                     word, ent, k_w, k_b, v_w, v_b, Kb, Vb);
  hipLaunchKernelGGL(attn_fq, dim3(9,12), dim3(256), 0, stream,
                     Kb, Vb, word, ent, q_w, q_b, w2e_w, w2e_b,
                     e2w_w, e2w_b, e2e_w, e2e_b, am, outw, oute);
}

// Round 8
// 273.242 us; speedup vs baseline: 8.1148x; 8.1148x over previous
//
#include <hip/hip_runtime.h>

typedef __bf16 bf16x8 __attribute__((ext_vector_type(8)));
typedef unsigned short u16x8 __attribute__((ext_vector_type(8)));
typedef u16x8 u16x8_a __attribute__((may_alias));
typedef float f32x4 __attribute__((ext_vector_type(4)));

#define LOG2E 1.4426950408889634f
#define NEGV  -10000.0f

__device__ __forceinline__ float bf2f(unsigned short u){
  union{unsigned int i; float f;} x; x.i = ((unsigned int)u)<<16; return x.f;
}
__device__ __forceinline__ unsigned short f2bf(float f){
  union{float f; unsigned int i;} x; x.f=f;
  unsigned int i = x.i;
  return (unsigned short)((i + 0x7FFFu + ((i>>16)&1u)) >> 16);
}
__device__ __forceinline__ u16x8 cvt8(float4 a, float4 b){
  u16x8 r;
  r[0]=f2bf(a.x); r[1]=f2bf(a.y); r[2]=f2bf(a.z); r[3]=f2bf(a.w);
  r[4]=f2bf(b.x); r[5]=f2bf(b.y); r[6]=f2bf(b.z); r[7]=f2bf(b.w);
  return r;
}

// ---------------- weight transpose+cast: wT[g][n][k] = bf16(w[g][k][n]), 768x768 ----------------
__global__ __launch_bounds__(256) void transpose6(
    const float* __restrict__ w0, const float* __restrict__ w1,
    const float* __restrict__ w2, const float* __restrict__ w3,
    const float* __restrict__ w4, const float* __restrict__ w5,
    unsigned short* __restrict__ outT)
{
  const float* src;
  switch (blockIdx.z){
    case 0: src = w0; break; case 1: src = w1; break; case 2: src = w2; break;
    case 3: src = w3; break; case 4: src = w4; break; default: src = w5; break;
  }
  unsigned short* dst = outT + (size_t)blockIdx.z * 589824;
  __shared__ float tile[32][33];
  int tx = threadIdx.x, ty = threadIdx.y;
  int x0 = blockIdx.x*32, y0 = blockIdx.y*32;
  #pragma unroll
  for (int i=0;i<32;i+=8) tile[ty+i][tx] = src[(size_t)(y0+ty+i)*768 + x0+tx];
  __syncthreads();
  #pragma unroll
  for (int i=0;i<32;i+=8) dst[(size_t)(x0+ty+i)*768 + y0+tx] = f2bf(tile[tx][ty+i]);
}

// ---------------- batched projection GEMM: out = bf16(A fp32) @ wT(bf16) + bias(fp32) ----------------
// g order: 0=K 1=V (A=concat, 17 mtiles) 2=Q 3=W2E (A=word, 16) 4=E2W 5=E2E (A=ent, 1)
__global__ __launch_bounds__(256) void gemm_proj(
    const float* __restrict__ word, const float* __restrict__ ent,
    const unsigned short* __restrict__ wT,
    const float* __restrict__ bK, const float* __restrict__ bV,
    const float* __restrict__ bQ, const float* __restrict__ bWE,
    const float* __restrict__ bEW, const float* __restrict__ bEE,
    unsigned short* __restrict__ oK, unsigned short* __restrict__ oV,
    unsigned short* __restrict__ oQ, unsigned short* __restrict__ oWE,
    unsigned short* __restrict__ oEW, unsigned short* __restrict__ oEE)
{
  int mt = blockIdx.x, ntile = blockIdx.y;
  int g, mg;
  if      (mt < 17){ g=0; mg=mt;    }
  else if (mt < 34){ g=1; mg=mt-17; }
  else if (mt < 50){ g=2; mg=mt-34; }
  else if (mt < 66){ g=3; mg=mt-50; }
  else if (mt < 67){ g=4; mg=0;     }
  else             { g=5; mg=0;     }
  int m0 = mg*128;
  const float* A;
  if (g<=1)      A = (mg<16) ? (word + (size_t)m0*768) : ent;  // concat rows; tile16 = entities
  else if (g<=3) A = word + (size_t)m0*768;
  else           A = ent;
  const unsigned short* B = wT + (size_t)g*589824;
  const float* bias; unsigned short* out;
  switch (g){
    case 0: bias=bK;  out=oK;  break;
    case 1: bias=bV;  out=oV;  break;
    case 2: bias=bQ;  out=oQ;  break;
    case 3: bias=bWE; out=oWE; break;
    case 4: bias=bEW; out=oEW; break;
    default:bias=bEE; out=oEE; break;
  }
  out += (size_t)m0*768;
  int n0 = ntile*128;

  __shared__ __align__(16) unsigned short a_s[128*32];  // [m][k] bf16
  __shared__ __align__(16) unsigned short b_s[128*32];  // [n][k] bf16

  int tid  = threadIdx.x;
  int w    = tid>>6, lane = tid&63, quad = lane>>4, lr = lane&15;
  int wm   = (w&1)*64, wn = (w>>1)*64;

  f32x4 acc[4][4];
  #pragma unroll
  for (int i=0;i<4;i++) for (int j=0;j<4;j++) for (int r=0;r<4;r++) acc[i][j][r]=0.f;

  int ar = tid>>1;            // staging row 0..127
  int ak = (tid&1)*16;        // staging col base {0,16}
  const float* Arow = A + (size_t)ar*768 + ak;
  const unsigned short* Brow = B + (size_t)(n0+ar)*768 + ak;

  for (int k0=0; k0<768; k0+=32){
    float4 af0 = *(const float4*)(Arow + k0);
    float4 af1 = *(const float4*)(Arow + k0 + 4);
    float4 af2 = *(const float4*)(Arow + k0 + 8);
    float4 af3 = *(const float4*)(Arow + k0 + 12);
    u16x8 av0 = cvt8(af0, af1);
    u16x8 av1 = cvt8(af2, af3);
    u16x8 bv0 = *(const u16x8_a*)(Brow + k0);
    u16x8 bv1 = *(const u16x8_a*)(Brow + k0 + 8);
    __syncthreads();
    *(u16x8_a*)(a_s + ar*32 + ak)     = av0;
    *(u16x8_a*)(a_s + ar*32 + ak + 8) = av1;
    *(u16x8_a*)(b_s + ar*32 + ak)     = bv0;
    *(u16x8_a*)(b_s + ar*32 + ak + 8) = bv1;
    __syncthreads();
    bf16x8 af[4], bfr[4];
    #pragma unroll
    for (int i=0;i<4;i++)
      af[i]  = __builtin_bit_cast(bf16x8, *(const u16x8_a*)(a_s + (wm+i*16+lr)*32 + quad*8));
    #pragma unroll
    for (int i=0;i<4;i++)
      bfr[i] = __builtin_bit_cast(bf16x8, *(const u16x8_a*)(b_s + (wn+i*16+lr)*32 + quad*8));
    #pragma unroll
    for (int i=0;i<4;i++)
      #pragma unroll
      for (int j=0;j<4;j++)
        acc[i][j] = __builtin_amdgcn_mfma_f32_16x16x32_bf16(af[i], bfr[j], acc[i][j], 0,0,0);
  }
  #pragma unroll
  for (int j=0;j<4;j++){
    int col = n0 + wn + j*16 + lr;
    float bb = bias[col];
    #pragma unroll
    for (int i=0;i<4;i++){
      int rowb = wm + i*16 + quad*4;
      #pragma unroll
      for (int r=0;r<4;r++)
        out[(size_t)(rowb+r)*768 + col] = f2bf(acc[i][j][r] + bb);
    }
  }
}

// ---------------- fused MFMA flash attention (word + entity queries), fp32 output ----
// blocks 0..31: word q-tiles (64 q each); blocks 32..33: entity q-tiles
__global__ __launch_bounds__(256) void attn_fused(
  const unsigned short* __restrict__ Kb,  const unsigned short* __restrict__ Vb,
  const unsigned short* __restrict__ Qw,  const unsigned short* __restrict__ Qwe,
  const unsigned short* __restrict__ Qew, const unsigned short* __restrict__ Qee,
  const float* __restrict__ am,
  float* __restrict__ outw, float* __restrict__ oute)
{
  int bx = blockIdx.x, h = blockIdx.y;
  bool isword = bx < 32;
  int q0 = isword ? bx*64 : (bx-32)*64;
  const unsigned short* Qa = isword ? Qw  : Qew;   // used vs word keys
  const unsigned short* Qb = isword ? Qwe : Qee;   // used vs entity keys
  float* outp = isword ? outw : oute;

  int tid = threadIdx.x, w = tid>>6, lane = tid&63, quad = lane>>4, lr = lane&15;
  int qrb = q0 + w*16;   // this wave's 16 query rows

  __shared__ __align__(16) unsigned short k_s[32*64];     // [key][dim]
  __shared__ __align__(16) unsigned short vT_s[64*32];    // [dim][key]
  __shared__ __align__(16) unsigned short p_s[4*16*32];   // per-wave P

  const unsigned short* qrow = Qa + (size_t)(qrb+lr)*768 + h*64 + quad*8;
  bf16x8 qa0 = __builtin_bit_cast(bf16x8, *(const u16x8_a*)(qrow));
  bf16x8 qa1 = __builtin_bit_cast(bf16x8, *(const u16x8_a*)(qrow + 32));
  qrow = Qb + (size_t)(qrb+lr)*768 + h*64 + quad*8;
  bf16x8 qb0 = __builtin_bit_cast(bf16x8, *(const u16x8_a*)(qrow));
  bf16x8 qb1 = __builtin_bit_cast(bf16x8, *(const u16x8_a*)(qrow + 32));

  float m_r[4], l_r[4];
  f32x4 o[4];
  #pragma unroll
  for (int r=0;r<4;r++){ m_r[r] = -1e30f; l_r[r] = 0.f; }
  #pragma unroll
  for (int n2=0;n2<4;n2++) for (int r=0;r<4;r++) o[n2][r] = 0.f;

  int wlo, whi;
  if (isword){ wlo = q0-256; if (wlo<0) wlo=0; whi = q0+63+256; if (whi>2047) whi=2047; }
  else       { wlo = 0; whi = 2047; }
  int nw = (whi + 1 - wlo) >> 5;   // spans are 32-aligned
  int nc = nw + 4;                 // + 128 entity keys

  int skey = tid>>3, sd = (tid&7)*8;

  for (int c=0;c<nc;c++){
    int j0 = (c<nw) ? (wlo + c*32) : (2048 + (c-nw)*32);
    bool entp = c >= nw;
    __syncthreads();
    {
      const unsigned short* kp = Kb + (size_t)(j0+skey)*768 + h*64 + sd;
      const unsigned short* vp = Vb + (size_t)(j0+skey)*768 + h*64 + sd;
      u16x8 kv = *(const u16x8_a*)kp;
      u16x8 vv = *(const u16x8_a*)vp;
      *(u16x8_a*)(k_s + skey*64 + sd) = kv;
      #pragma unroll
      for (int d=0; d<8; d++) vT_s[(sd+d)*32 + skey] = vv[d];  // transpose V
    }
    __syncthreads();

    bf16x8 qf0 = entp ? qb0 : qa0;
    bf16x8 qf1 = entp ? qb1 : qa1;
    f32x4 s[2];
    #pragma unroll
    for (int t=0;t<2;t++){
      bf16x8 kf0 = __builtin_bit_cast(bf16x8, *(const u16x8_a*)(k_s + (t*16+lr)*64 + quad*8));
      bf16x8 kf1 = __builtin_bit_cast(bf16x8, *(const u16x8_a*)(k_s + (t*16+lr)*64 + 32 + quad*8));
      f32x4 z; for (int r=0;r<4;r++) z[r]=0.f;
      z = __builtin_amdgcn_mfma_f32_16x16x32_bf16(qf0, kf0, z, 0,0,0);
      z = __builtin_amdgcn_mfma_f32_16x16x32_bf16(qf1, kf1, z, 0,0,0);
      s[t] = z;
    }

    float sc[2][4];
    bool wband = isword && !entp;
    #pragma unroll
    for (int t=0;t<2;t++){
      int j = j0 + t*16 + lr;      // this lane's key (col = lane&15)
      float amj  = am[j];
      float addl = amj * LOG2E;    // + attention_mask after /8 (log2 domain)
      #pragma unroll
      for (int r=0;r<4;r++){
        float sv = s[t][r];
        if (wband){
          sv += (amj != 0.f) ? NEGV : 0.f;                    // float_mask pre-add
          int i = qrb + quad*4 + r;
          bool ok = ((unsigned)(i - j + 256) <= 512u) && (sv != 0.f);  // band & !=0 quirk
          sv = ok ? sv : NEGV;
        }
        sc[t][r] = sv * (LOG2E*0.125f) + addl;
      }
    }

    #pragma unroll
    for (int r=0;r<4;r++){
      float mx = fmaxf(sc[0][r], sc[1][r]);
      mx = fmaxf(mx, __shfl_xor(mx, 1));
      mx = fmaxf(mx, __shfl_xor(mx, 2));
      mx = fmaxf(mx, __shfl_xor(mx, 4));
      mx = fmaxf(mx, __shfl_xor(mx, 8));
      float mn = fmaxf(m_r[r], mx);
      float alpha = exp2f(m_r[r] - mn);
      m_r[r] = mn;
      float p0 = exp2f(sc[0][r]-mn), p1 = exp2f(sc[1][r]-mn);
      unsigned short pb0 = f2bf(p0), pb1 = f2bf(p1);
      float rs = bf2f(pb0) + bf2f(pb1);   // sum the bf16-rounded values for P/l consistency
      rs += __shfl_xor(rs,1); rs += __shfl_xor(rs,2);
      rs += __shfl_xor(rs,4); rs += __shfl_xor(rs,8);
      l_r[r] = l_r[r]*alpha + rs;
      p_s[w*512 + (quad*4+r)*32 + lr]      = pb0;
      p_s[w*512 + (quad*4+r)*32 + 16 + lr] = pb1;
      #pragma unroll
      for (int n2=0;n2<4;n2++) o[n2][r] *= alpha;
    }

    // P (C-layout) -> A-frag via LDS round-trip; barrier fences the typed accesses.
    __syncthreads();
    bf16x8 pf = __builtin_bit_cast(bf16x8, *(const u16x8_a*)(p_s + w*512 + lr*32 + quad*8));
    #pragma unroll
    for (int n2=0;n2<4;n2++){
      bf16x8 vf = __builtin_bit_cast(bf16x8, *(const u16x8_a*)(vT_s + (n2*16+lr)*32 + quad*8));
      o[n2] = __builtin_amdgcn_mfma_f32_16x16x32_bf16(pf, vf, o[n2], 0,0,0);
    }
  }

  #pragma unroll
  for (int n2=0;n2<4;n2++){
    #pragma unroll
    for (int r=0;r<4;r++){
      int row = qrb + quad*4 + r;
      float val = o[n2][r] / l_r[r];
      outp[(size_t)row*768 + h*64 + n2*16 + lr] = val;   // fp32 output
    }
  }
}

extern "C" void kernel_launch(void* const* d_in, const int* in_sizes, int n_in,
                              void* d_out, int out_size, void* d_ws, size_t ws_size,
                              hipStream_t stream) {
  const float* word  = (const float*)d_in[0];
  const float* ent   = (const float*)d_in[1];
  const float* am    = (const float*)d_in[2];
  const float* q_w   = (const float*)d_in[3];
  const float* q_b   = (const float*)d_in[4];
  const float* k_w   = (const float*)d_in[5];
  const float* k_b   = (const float*)d_in[6];
  const float* v_w   = (const float*)d_in[7];
  const float* v_b   = (const float*)d_in[8];
  const float* w2e_w = (const float*)d_in[9];
  const float* w2e_b = (const float*)d_in[10];
  const float* e2w_w = (const float*)d_in[11];
  const float* e2w_b = (const float*)d_in[12];
  const float* e2e_w = (const float*)d_in[13];
  const float* e2e_b = (const float*)d_in[14];

  unsigned short* ws  = (unsigned short*)d_ws;
  unsigned short* wT  = ws;                       // 6*768*768 bf16
  unsigned short* Kb  = wT  + (size_t)6*589824;   // 2176*768
  unsigned short* Vb  = Kb  + (size_t)2176*768;
  unsigned short* Qw  = Vb  + (size_t)2176*768;   // 2048*768
  unsigned short* Qwe = Qw  + (size_t)2048*768;
  unsigned short* Qew = Qwe + (size_t)2048*768;   // 128*768
  unsigned short* Qee = Qew + (size_t)128*768;

  float* outw = (float*)d_out;                    // fp32 output (confirmed R7)
  float* oute = outw + (size_t)2048*768;

  hipLaunchKernelGGL(transpose6, dim3(24,24,6), dim3(32,8), 0, stream,
                     k_w, v_w, q_w, w2e_w, e2w_w, e2e_w, wT);
  hipLaunchKernelGGL(gemm_proj, dim3(68,6), dim3(256), 0, stream,
                     word, ent, wT, k_b, v_b, q_b, w2e_b, e2w_b, e2e_b,
                     Kb, Vb, Qw, Qwe, Qew, Qee);
  hipLaunchKernelGGL(attn_fused, dim3(34,12), dim3(256), 0, stream,
                     Kb, Vb, Qw, Qwe, Qew, Qee, am, outw, oute);
}

// Round 9
// 183.398 us; speedup vs baseline: 12.0902x; 1.4899x over previous
//
#include <hip/hip_runtime.h>

typedef __bf16 bf16x8 __attribute__((ext_vector_type(8)));
typedef unsigned short u16x8 __attribute__((ext_vector_type(8)));
typedef u16x8 u16x8_a __attribute__((may_alias));
typedef unsigned int u32x4 __attribute__((ext_vector_type(4)));
typedef u32x4 u32x4_a __attribute__((may_alias));
typedef float f32x4 __attribute__((ext_vector_type(4)));

#define LOG2E 1.4426950408889634f
#define NEGV  -10000.0f

__device__ __forceinline__ float bf2f(unsigned short u){
  union{unsigned int i; float f;} x; x.i = ((unsigned int)u)<<16; return x.f;
}
__device__ __forceinline__ unsigned short f2bf(float f){
  union{float f; unsigned int i;} x; x.f=f;
  unsigned int i = x.i;
  return (unsigned short)((i + 0x7FFFu + ((i>>16)&1u)) >> 16);
}
__device__ __forceinline__ u16x8 cvt8(float4 a, float4 b){
  u16x8 r;
  r[0]=f2bf(a.x); r[1]=f2bf(a.y); r[2]=f2bf(a.z); r[3]=f2bf(a.w);
  r[4]=f2bf(b.x); r[5]=f2bf(b.y); r[6]=f2bf(b.z); r[7]=f2bf(b.w);
  return r;
}
__device__ __forceinline__ bf16x8 ldb(const unsigned short* p){
  return __builtin_bit_cast(bf16x8, *(const u16x8_a*)p);
}

// ---------------- weight transpose+cast: wT[g][n][k] = bf16(w[g][k][n]), 768x768 ----------------
__global__ __launch_bounds__(256) void transpose6(
    const float* __restrict__ w0, const float* __restrict__ w1,
    const float* __restrict__ w2, const float* __restrict__ w3,
    const float* __restrict__ w4, const float* __restrict__ w5,
    unsigned short* __restrict__ outT)
{
  const float* src;
  switch (blockIdx.z){
    case 0: src = w0; break; case 1: src = w1; break; case 2: src = w2; break;
    case 3: src = w3; break; case 4: src = w4; break; default: src = w5; break;
  }
  unsigned short* dst = outT + (size_t)blockIdx.z * 589824;
  __shared__ float tile[32][33];
  int tx = threadIdx.x, ty = threadIdx.y;
  int x0 = blockIdx.x*32, y0 = blockIdx.y*32;
  #pragma unroll
  for (int i=0;i<32;i+=8) tile[ty+i][tx] = src[(size_t)(y0+ty+i)*768 + x0+tx];
  __syncthreads();
  #pragma unroll
  for (int i=0;i<32;i+=8) dst[(size_t)(x0+ty+i)*768 + y0+tx] = f2bf(tile[tx][ty+i]);
}

// ---------------- V transpose: VbT[d][key] = Vb[key][d] (bf16, 2176x768 -> 768x2176) ----
__global__ __launch_bounds__(256) void transpose_v(
    const unsigned short* __restrict__ Vb, unsigned short* __restrict__ VbT)
{
  __shared__ unsigned short t[32][33];
  int tx = threadIdx.x, ty = threadIdx.y;
  int x0 = blockIdx.x*32;   // key
  int y0 = blockIdx.y*32;   // dim
  #pragma unroll
  for (int i=0;i<32;i+=8) t[ty+i][tx] = Vb[(size_t)(x0+ty+i)*768 + y0+tx];
  __syncthreads();
  #pragma unroll
  for (int i=0;i<32;i+=8) VbT[(size_t)(y0+ty+i)*2176 + x0+tx] = t[tx][ty+i];
}

// ---------------- batched projection GEMM: out = bf16(A fp32) @ wT(bf16) + bias(fp32) ----------------
__global__ __launch_bounds__(256) void gemm_proj(
    const float* __restrict__ word, const float* __restrict__ ent,
    const unsigned short* __restrict__ wT,
    const float* __restrict__ bK, const float* __restrict__ bV,
    const float* __restrict__ bQ, const float* __restrict__ bWE,
    const float* __restrict__ bEW, const float* __restrict__ bEE,
    unsigned short* __restrict__ oK, unsigned short* __restrict__ oV,
    unsigned short* __restrict__ oQ, unsigned short* __restrict__ oWE,
    unsigned short* __restrict__ oEW, unsigned short* __restrict__ oEE)
{
  int mt = blockIdx.x, ntile = blockIdx.y;
  int g, mg;
  if      (mt < 17){ g=0; mg=mt;    }
  else if (mt < 34){ g=1; mg=mt-17; }
  else if (mt < 50){ g=2; mg=mt-34; }
  else if (mt < 66){ g=3; mg=mt-50; }
  else if (mt < 67){ g=4; mg=0;     }
  else             { g=5; mg=0;     }
  int m0 = mg*128;
  const float* A;
  if (g<=1)      A = (mg<16) ? (word + (size_t)m0*768) : ent;
  else if (g<=3) A = word + (size_t)m0*768;
  else           A = ent;
  const unsigned short* B = wT + (size_t)g*589824;
  const float* bias; unsigned short* out;
  switch (g){
    case 0: bias=bK;  out=oK;  break;
    case 1: bias=bV;  out=oV;  break;
    case 2: bias=bQ;  out=oQ;  break;
    case 3: bias=bWE; out=oWE; break;
    case 4: bias=bEW; out=oEW; break;
    default:bias=bEE; out=oEE; break;
  }
  out += (size_t)m0*768;
  int n0 = ntile*128;

  __shared__ __align__(16) unsigned short a_s[128*32];
  __shared__ __align__(16) unsigned short b_s[128*32];

  int tid  = threadIdx.x;
  int w    = tid>>6, lane = tid&63, quad = lane>>4, lr = lane&15;
  int wm   = (w&1)*64, wn = (w>>1)*64;

  f32x4 acc[4][4];
  #pragma unroll
  for (int i=0;i<4;i++) for (int j=0;j<4;j++) for (int r=0;r<4;r++) acc[i][j][r]=0.f;

  int ar = tid>>1;
  int ak = (tid&1)*16;
  const float* Arow = A + (size_t)ar*768 + ak;
  const unsigned short* Brow = B + (size_t)(n0+ar)*768 + ak;

  for (int k0=0; k0<768; k0+=32){
    float4 af0 = *(const float4*)(Arow + k0);
    float4 af1 = *(const float4*)(Arow + k0 + 4);
    float4 af2 = *(const float4*)(Arow + k0 + 8);
    float4 af3 = *(const float4*)(Arow + k0 + 12);
    u16x8 av0 = cvt8(af0, af1);
    u16x8 av1 = cvt8(af2, af3);
    u16x8 bv0 = *(const u16x8_a*)(Brow + k0);
    u16x8 bv1 = *(const u16x8_a*)(Brow + k0 + 8);
    __syncthreads();
    *(u16x8_a*)(a_s + ar*32 + ak)     = av0;
    *(u16x8_a*)(a_s + ar*32 + ak + 8) = av1;
    *(u16x8_a*)(b_s + ar*32 + ak)     = bv0;
    *(u16x8_a*)(b_s + ar*32 + ak + 8) = bv1;
    __syncthreads();
    bf16x8 af[4], bfr[4];
    #pragma unroll
    for (int i=0;i<4;i++) af[i]  = ldb(a_s + (wm+i*16+lr)*32 + quad*8);
    #pragma unroll
    for (int i=0;i<4;i++) bfr[i] = ldb(b_s + (wn+i*16+lr)*32 + quad*8);
    #pragma unroll
    for (int i=0;i<4;i++)
      #pragma unroll
      for (int j=0;j<4;j++)
        acc[i][j] = __builtin_amdgcn_mfma_f32_16x16x32_bf16(af[i], bfr[j], acc[i][j], 0,0,0);
  }
  #pragma unroll
  for (int j=0;j<4;j++){
    int col = n0 + wn + j*16 + lr;
    float bb = bias[col];
    #pragma unroll
    for (int i=0;i<4;i++){
      int rowb = wm + i*16 + quad*4;
      #pragma unroll
      for (int r=0;r<4;r++)
        out[(size_t)(rowb+r)*768 + col] = f2bf(acc[i][j][r] + bb);
    }
  }
}

// ---------------- barrier-free split-key MFMA flash attention, fp32 output ----------------
// blocks 0..63: word, 32 q rows each (2 groups x 16 rows, key-split 2 ways)
// blocks 64..71: entity, 16 q rows each (key-split 4 ways). grid.y = head.
__global__ __launch_bounds__(256) void attn_split(
  const unsigned short* __restrict__ Kb,  const unsigned short* __restrict__ VbT,
  const unsigned short* __restrict__ Qw,  const unsigned short* __restrict__ Qwe,
  const unsigned short* __restrict__ Qew, const unsigned short* __restrict__ Qee,
  const float* __restrict__ am,
  float* __restrict__ outw, float* __restrict__ oute)
{
  int bx = blockIdx.x, h = blockIdx.y;
  int tid = threadIdx.x, w = tid>>6, lane = tid&63, quad = lane>>4, lr = lane&15;
  bool isword = bx < 64;
  int qrb, kh, nsplit;
  const unsigned short *Qa, *Qb;
  float* outp;
  if (isword){ qrb = bx*32 + (w>>1)*16; kh = w&1; nsplit = 2; Qa=Qw;  Qb=Qwe; outp=outw; }
  else       { qrb = (bx-64)*16;        kh = w;   nsplit = 4; Qa=Qew; Qb=Qee; outp=oute; }

  __shared__ __align__(16) unsigned int p32[4][16*24];  // packed P, stride 24 (2-way banks)
  __shared__ float mrg[4][64][24];                      // merge buffer (epilogue only)

  const unsigned short* qr = Qa + (size_t)(qrb+lr)*768 + h*64 + quad*8;
  bf16x8 qa0 = ldb(qr), qa1 = ldb(qr + 32);
  qr = Qb + (size_t)(qrb+lr)*768 + h*64 + quad*8;
  bf16x8 qb0 = ldb(qr), qb1 = ldb(qr + 32);

  float m_r[4], l_r[4];
  f32x4 o[4];
  #pragma unroll
  for (int r=0;r<4;r++){ m_r[r] = -1e30f; l_r[r] = 0.f; }
  #pragma unroll
  for (int n2=0;n2<4;n2++) for (int r=0;r<4;r++) o[n2][r] = 0.f;

  int lo, nw;
  if (isword){
    lo = qrb - 256; if (lo < 0) lo = 0; lo &= ~31;        // padded keys are band-masked
    int hi = qrb + 272; if (hi > 2048) hi = 2048; hi = (hi + 31) & ~31;
    nw = (hi - lo) >> 5;
  } else { lo = 0; nw = 64; }
  int nc = nw + 4;

  for (int c = kh; c < nc; c += nsplit){
    bool entp = c >= nw;
    int j0 = entp ? (2048 + (c-nw)*32) : (lo + c*32);

    // K B-frags direct from global (Kb is [key][dim] = B-layout)
    const unsigned short* kp = Kb + (size_t)(j0+lr)*768 + h*64 + quad*8;
    bf16x8 k00 = ldb(kp),          k01 = ldb(kp + 32);
    bf16x8 k10 = ldb(kp + 16*768), k11 = ldb(kp + 16*768 + 32);
    // V B-frags direct from global (VbT is [dim][key] = B-layout for PV)
    const unsigned short* vp = VbT + (size_t)(h*64 + lr)*2176 + j0 + quad*8;
    bf16x8 v0 = ldb(vp), v1 = ldb(vp + 16*2176), v2 = ldb(vp + 32*2176), v3 = ldb(vp + 48*2176);

    bf16x8 qf0 = entp ? qb0 : qa0;
    bf16x8 qf1 = entp ? qb1 : qa1;
    f32x4 s[2];
    {
      f32x4 z0 = {0.f,0.f,0.f,0.f}, z1 = {0.f,0.f,0.f,0.f};
      z0 = __builtin_amdgcn_mfma_f32_16x16x32_bf16(qf0, k00, z0, 0,0,0);
      z0 = __builtin_amdgcn_mfma_f32_16x16x32_bf16(qf1, k01, z0, 0,0,0);
      z1 = __builtin_amdgcn_mfma_f32_16x16x32_bf16(qf0, k10, z1, 0,0,0);
      z1 = __builtin_amdgcn_mfma_f32_16x16x32_bf16(qf1, k11, z1, 0,0,0);
      s[0] = z0; s[1] = z1;
    }

    float sc[2][4];
    bool wband = isword && !entp;
    #pragma unroll
    for (int t=0;t<2;t++){
      int j = j0 + t*16 + lr;
      float amj  = am[j];
      float addl = amj * LOG2E;
      #pragma unroll
      for (int r=0;r<4;r++){
        float sv = s[t][r];
        if (wband){
          sv += (amj != 0.f) ? NEGV : 0.f;                              // float_mask pre-add
          int i = qrb + quad*4 + r;
          bool ok = ((unsigned)(i - j + 256) <= 512u) && (sv != 0.f);   // band & !=0 quirk
          sv = ok ? sv : NEGV;
        }
        sc[t][r] = sv * (LOG2E*0.125f) + addl;
      }
    }

    #pragma unroll
    for (int r=0;r<4;r++){
      float mx = fmaxf(sc[0][r], sc[1][r]);
      mx = fmaxf(mx, __shfl_xor(mx, 1));
      mx = fmaxf(mx, __shfl_xor(mx, 2));
      mx = fmaxf(mx, __shfl_xor(mx, 4));
      mx = fmaxf(mx, __shfl_xor(mx, 8));
      float mn = fmaxf(m_r[r], mx);
      float alpha = exp2f(m_r[r] - mn);
      m_r[r] = mn;
      float p0 = exp2f(sc[0][r]-mn), p1 = exp2f(sc[1][r]-mn);
      unsigned short pb0 = f2bf(p0), pb1 = f2bf(p1);
      float rs = bf2f(pb0) + bf2f(pb1);
      rs += __shfl_xor(rs,1); rs += __shfl_xor(rs,2);
      rs += __shfl_xor(rs,4); rs += __shfl_xor(rs,8);
      l_r[r] = l_r[r]*alpha + rs;
      p32[w][(quad*4+r)*24 + lr] = (unsigned int)pb0 | ((unsigned int)pb1 << 16);
      #pragma unroll
      for (int n2=0;n2<4;n2++) o[n2][r] *= alpha;
    }

    // P (C-layout) -> A-frag, wave-local LDS round-trip (no barrier needed)
    const unsigned int* pbp = &p32[w][lr*24 + (quad&1)*8];
    u32x4 ra = *(const u32x4_a*)pbp;
    u32x4 rb = *(const u32x4_a*)(pbp + 4);
    unsigned int pf32[4];
    if (quad < 2){
      pf32[0] = (ra[0]&0xFFFFu) | (ra[1]<<16);
      pf32[1] = (ra[2]&0xFFFFu) | (ra[3]<<16);
      pf32[2] = (rb[0]&0xFFFFu) | (rb[1]<<16);
      pf32[3] = (rb[2]&0xFFFFu) | (rb[3]<<16);
    } else {
      pf32[0] = (ra[0]>>16) | (ra[1]&0xFFFF0000u);
      pf32[1] = (ra[2]>>16) | (ra[3]&0xFFFF0000u);
      pf32[2] = (rb[0]>>16) | (rb[1]&0xFFFF0000u);
      pf32[3] = (rb[2]>>16) | (rb[3]&0xFFFF0000u);
    }
    u32x4 pfv = {pf32[0], pf32[1], pf32[2], pf32[3]};
    bf16x8 pf = __builtin_bit_cast(bf16x8, pfv);

    o[0] = __builtin_amdgcn_mfma_f32_16x16x32_bf16(pf, v0, o[0], 0,0,0);
    o[1] = __builtin_amdgcn_mfma_f32_16x16x32_bf16(pf, v1, o[1], 0,0,0);
    o[2] = __builtin_amdgcn_mfma_f32_16x16x32_bf16(pf, v2, o[2], 0,0,0);
    o[3] = __builtin_amdgcn_mfma_f32_16x16x32_bf16(pf, v3, o[3], 0,0,0);
  }

  // ---- cross-wave merge (single barrier) ----
  {
    float* my = &mrg[w][lane][0];
    #pragma unroll
    for (int r=0;r<4;r++){ my[r] = m_r[r]; my[4+r] = l_r[r]; }
    #pragma unroll
    for (int n2=0;n2<4;n2++)
      #pragma unroll
      for (int r=0;r<4;r++) my[8+n2*4+r] = o[n2][r];
  }
  __syncthreads();
  if (kh == 0){
    for (int p=1; p<nsplit; p++){
      const float* pr = &mrg[w+p][lane][0];
      #pragma unroll
      for (int r=0;r<4;r++){
        float m2 = pr[r], l2 = pr[4+r];
        float M  = fmaxf(m_r[r], m2);
        float e1 = exp2f(m_r[r]-M), e2 = exp2f(m2-M);
        m_r[r] = M;
        l_r[r] = l_r[r]*e1 + l2*e2;
        #pragma unroll
        for (int n2=0;n2<4;n2++)
          o[n2][r] = o[n2][r]*e1 + pr[8+n2*4+r]*e2;
      }
    }
    #pragma unroll
    for (int n2=0;n2<4;n2++)
      #pragma unroll
      for (int r=0;r<4;r++){
        int row = qrb + quad*4 + r;
        outp[(size_t)row*768 + h*64 + n2*16 + lr] = o[n2][r] / l_r[r];
      }
  }
}

extern "C" void kernel_launch(void* const* d_in, const int* in_sizes, int n_in,
                              void* d_out, int out_size, void* d_ws, size_t ws_size,
                              hipStream_t stream) {
  const float* word  = (const float*)d_in[0];
  const float* ent   = (const float*)d_in[1];
  const float* am    = (const float*)d_in[2];
  const float* q_w   = (const float*)d_in[3];
  const float* q_b   = (const float*)d_in[4];
  const float* k_w   = (const float*)d_in[5];
  const float* k_b   = (const float*)d_in[6];
  const float* v_w   = (const float*)d_in[7];
  const float* v_b   = (const float*)d_in[8];
  const float* w2e_w = (const float*)d_in[9];
  const float* w2e_b = (const float*)d_in[10];
  const float* e2w_w = (const float*)d_in[11];
  const float* e2w_b = (const float*)d_in[12];
  const float* e2e_w = (const float*)d_in[13];
  const float* e2e_b = (const float*)d_in[14];

  unsigned short* ws  = (unsigned short*)d_ws;
  unsigned short* wT  = ws;                       // 6*768*768 bf16
  unsigned short* Kb  = wT  + (size_t)6*589824;   // 2176*768
  unsigned short* Vb  = Kb  + (size_t)2176*768;
  unsigned short* Qw  = Vb  + (size_t)2176*768;   // 2048*768
  unsigned short* Qwe = Qw  + (size_t)2048*768;
  unsigned short* Qew = Qwe + (size_t)2048*768;   // 128*768
  unsigned short* Qee = Qew + (size_t)128*768;
  unsigned short* VbT = Qee + (size_t)128*768;    // 768*2176

  float* outw = (float*)d_out;                    // fp32 output
  float* oute = outw + (size_t)2048*768;

  hipLaunchKernelGGL(transpose6, dim3(24,24,6), dim3(32,8), 0, stream,
                     k_w, v_w, q_w, w2e_w, e2w_w, e2e_w, wT);
  hipLaunchKernelGGL(gemm_proj, dim3(68,6), dim3(256), 0, stream,
                     word, ent, wT, k_b, v_b, q_b, w2e_b, e2w_b, e2e_b,
                     Kb, Vb, Qw, Qwe, Qew, Qee);
  hipLaunchKernelGGL(transpose_v, dim3(68,24), dim3(32,8), 0, stream, Vb, VbT);
  hipLaunchKernelGGL(attn_split, dim3(72,12), dim3(256), 0, stream,
                     Kb, VbT, Qw, Qwe, Qew, Qee, am, outw, oute);
}